// Round 2
// baseline (819.628 us; speedup 1.0000x reference)
//
#include <hip/hip_runtime.h>
#include <hip/hip_bf16.h>

typedef __attribute__((ext_vector_type(8))) short short8;
typedef __attribute__((ext_vector_type(4))) float floatx4;
typedef __attribute__((ext_vector_type(4))) unsigned short ushort4v;
typedef __attribute__((ext_vector_type(8))) unsigned short ushort8v;

#define N_DIM 12288
#define SPLITK 4
#define KCHUNK (N_DIM / SPLITK)   // 3072
#define KSTEP 64
#define KITERS (KCHUNK / KSTEP)   // 48
#define NTILE 64

__device__ __forceinline__ unsigned short f2bf(float f) {
  union { float f; unsigned int i; } x; x.f = f;
  unsigned int r = x.i + 0x7fffu + ((x.i >> 16) & 1u);   // RNE
  return (unsigned short)(r >> 16);
}

// ---------------------------------------------------------------------------
// Kernel 1: phi_part[s] = obs[64 x Kchunk_s] @ W[Kchunk_s x 12288] (+bias s==0)
// v3: raw s_barrier + counted s_waitcnt (no vmcnt(0) drain in the main loop),
// 2-deep register prefetch (two named reg sets, loop unrolled by 2), LDS
// double-buffer with ONE barrier per K-step. grid=(192,4), block=256.
// ---------------------------------------------------------------------------
__global__ __launch_bounds__(256) void gemm_phi(
    const float* __restrict__ obs, const float* __restrict__ W,
    const float* __restrict__ bias, float* __restrict__ phi_part)
{
  __shared__ unsigned short A_s[2][64 * 72];   // [buf][m][k], stride 72
  __shared__ unsigned short W_s[2][64 * 72];   // [buf][n][k] (transposed)

  const int t = threadIdx.x;
  const int n0 = blockIdx.x * NTILE;
  const int s  = blockIdx.y;
  const int k0 = s * KCHUNK;
  const int lane = t & 63, wv = t >> 6;
  const int l16 = lane & 15, q = lane >> 4;
  const int m0f = 16 * wv;

  const int am = t >> 2, akq = (t & 3) * 16;   // A staging: row, 16-col group
  const int rg = t >> 4, cg = t & 15;          // W staging: 4-row group, 4-col group

  const float* aptr = obs + (size_t)am * N_DIM + k0 + akq;
  const float* wptr = W + (size_t)(k0 + 4 * rg) * N_DIM + (n0 + 4 * cg);

  // two named register sets (NO runtime-indexed arrays -> stays in VGPRs)
  floatx4 pa0, pa1, pa2, pa3, pw0, pw1, pw2, pw3;   // set 0 (even tiles)
  floatx4 qa0, qa1, qa2, qa3, qw0, qw1, qw2, qw3;   // set 1 (odd tiles)

#define LOADS(A0, A1, A2, A3, W0, W1, W2, W3, TI) do {                       \
    const float* ap_ = aptr + (TI) * KSTEP;                                  \
    const float* wp_ = wptr + (size_t)(TI) * KSTEP * N_DIM;                  \
    A0 = *(const floatx4*)(ap_);       A1 = *(const floatx4*)(ap_ + 4);      \
    A2 = *(const floatx4*)(ap_ + 8);   A3 = *(const floatx4*)(ap_ + 12);     \
    W0 = *(const floatx4*)(wp_);               W1 = *(const floatx4*)(wp_ + N_DIM);     \
    W2 = *(const floatx4*)(wp_ + 2 * N_DIM);   W3 = *(const floatx4*)(wp_ + 3 * N_DIM); \
  } while (0)

  // prologue: tiles 0 and 1 in flight (16 outstanding loads)
  LOADS(pa0, pa1, pa2, pa3, pw0, pw1, pw2, pw3, 0);
  LOADS(qa0, qa1, qa2, qa3, qw0, qw1, qw2, qw3, 1);

  floatx4 acc[4];
#pragma unroll
  for (int i = 0; i < 4; i++) acc[i] = (floatx4){0.f, 0.f, 0.f, 0.f};

  // One K-step. Waits: oldest 8 loads (this tile) must be done -> vmcnt(8)
  // keeps the next tile's 8 loads in flight; only the last tile drains to 0.
#define STEP(TI, A0, A1, A2, A3, W0, W1, W2, W3, BUF, LAST) do {             \
    if (LAST) asm volatile("s_waitcnt vmcnt(0)" ::: "memory");               \
    else      asm volatile("s_waitcnt vmcnt(8)" ::: "memory");               \
    { /* convert regs -> LDS[BUF] */                                         \
      ushort8v u0, u1;                                                       \
      _Pragma("unroll")                                                      \
      for (int i = 0; i < 4; i++) {                                          \
        u0[i] = f2bf(A0[i]); u0[4 + i] = f2bf(A1[i]);                        \
        u1[i] = f2bf(A2[i]); u1[4 + i] = f2bf(A3[i]);                        \
      }                                                                      \
      *(ushort8v*)&A_s[BUF][am * 72 + akq]     = u0;                         \
      *(ushort8v*)&A_s[BUF][am * 72 + akq + 8] = u1;                         \
      _Pragma("unroll")                                                      \
      for (int i = 0; i < 4; i++) {                                          \
        ushort4v v = { f2bf(W0[i]), f2bf(W1[i]), f2bf(W2[i]), f2bf(W3[i]) }; \
        *(ushort4v*)&W_s[BUF][(4 * cg + i) * 72 + 4 * rg] = v;               \
      }                                                                      \
    }                                                                        \
    if ((TI) + 2 < KITERS) {  /* prefetch tile TI+2 into the freed set */    \
      LOADS(A0, A1, A2, A3, W0, W1, W2, W3, (TI) + 2);                       \
    }                                                                        \
    asm volatile("s_waitcnt lgkmcnt(0)" ::: "memory");  /* ds_writes + own prior ds_reads retired */ \
    __builtin_amdgcn_s_barrier();                                            \
    __builtin_amdgcn_sched_barrier(0);                                       \
    _Pragma("unroll")                                                        \
    for (int kk = 0; kk < 2; ++kk) {                                         \
      short8 af = *(const short8*)&A_s[BUF][(m0f + l16) * 72 + 32 * kk + 8 * q]; \
      _Pragma("unroll")                                                      \
      for (int nt = 0; nt < 4; ++nt) {                                       \
        short8 wf = *(const short8*)&W_s[BUF][(16 * nt + l16) * 72 + 32 * kk + 8 * q]; \
        acc[nt] = __builtin_amdgcn_mfma_f32_16x16x32_bf16(af, wf, acc[nt], 0, 0, 0); \
      }                                                                      \
    }                                                                        \
  } while (0)

  for (int it2 = 0; it2 < KITERS; it2 += 2) {
    STEP(it2,     pa0, pa1, pa2, pa3, pw0, pw1, pw2, pw3, 0, false);
    STEP(it2 + 1, qa0, qa1, qa2, qa3, qw0, qw1, qw2, qw3, 1, (it2 + 1 == KITERS - 1));
  }

  // epilogue: C/D layout col=lane&15, row=(lane>>4)*4+r  [m89/m91]; plain stores
  float* dst = phi_part + (size_t)s * 64 * N_DIM;
#pragma unroll
  for (int nt = 0; nt < 4; ++nt) {
    const int ncol = n0 + 16 * nt + l16;
    const float bv = (s == 0) ? bias[ncol] : 0.f;
#pragma unroll
    for (int r = 0; r < 4; ++r) {
      const int m = m0f + q * 4 + r;
      dst[(size_t)m * N_DIM + ncol] = acc[nt][r] + bv;
    }
  }
#undef STEP
#undef LOADS
}

// ---------------------------------------------------------------------------
// Kernel 2: per-batch softmax + K=64 VIN sweeps (ping-pong LDS) + argmax +
// patch + MLP. grid = 64 (one block per batch), block = 256 (4x4 cells/thread)
// sums the 4 split-K partial phi buffers on load.
// ---------------------------------------------------------------------------
#define VSTR 76
#define VOFF(h, w) (((h) + 1) * VSTR + (w) + 4)  // halo grid, interior 16B-aligned

__global__ __launch_bounds__(256) void vin_mlp(
    const float* __restrict__ obs, const float* __restrict__ phi,
    const float* __restrict__ w1, const float* __restrict__ b1,
    const float* __restrict__ w2, const float* __restrict__ b2,
    float* __restrict__ out)
{
  __shared__ float Vb[2][66 * VSTR];
  __shared__ float red_v[256];
  __shared__ int   red_i[256];

  const int b = blockIdx.x;
  const int t = threadIdx.x;
  const int ty = t >> 4, tx = t & 15;
  const int h0 = ty * 4, w0 = tx * 4;

  // zero both V buffers (halo must stay 0; interior = V0 = 0)
  for (int i = t; i < 2 * 66 * VSTR; i += 256) (&Vb[0][0])[i] = 0.f;

  // read phi rows (sum 4 split-K partials) -> rin/rout/logits for own 16 cells
  float rin[16], rout[16], lg[16];
#pragma unroll
  for (int r = 0; r < 4; r++) {
    const int j = 3 * ((h0 + r) * 64 + w0);   // 12 contiguous floats, 16B-aligned
    const float* base = phi + (size_t)b * N_DIM + j;
    floatx4 x0 = *(const floatx4*)(base);
    floatx4 x1 = *(const floatx4*)(base + 4);
    floatx4 x2 = *(const floatx4*)(base + 8);
#pragma unroll
    for (int sp = 1; sp < SPLITK; sp++) {
      const float* bs = base + (size_t)sp * 64 * N_DIM;
      x0 += *(const floatx4*)(bs);
      x1 += *(const floatx4*)(bs + 4);
      x2 += *(const floatx4*)(bs + 8);
    }
    float f[12];
#pragma unroll
    for (int c = 0; c < 4; c++) { f[c] = x0[c]; f[4 + c] = x1[c]; f[8 + c] = x2[c]; }
#pragma unroll
    for (int c = 0; c < 4; c++) {
      rin [r * 4 + c] = f[3 * c + 0];
      rout[r * 4 + c] = f[3 * c + 1];
      lg  [r * 4 + c] = f[3 * c + 2];
    }
  }

  // block softmax over the 4096 logits
  float lmax = -3.4e38f;
#pragma unroll
  for (int i = 0; i < 16; i++) lmax = fmaxf(lmax, lg[i]);
  __syncthreads();                       // zero-fill done
  red_v[t] = lmax; __syncthreads();
  for (int o = 128; o > 0; o >>= 1) { if (t < o) red_v[t] = fmaxf(red_v[t], red_v[t + o]); __syncthreads(); }
  const float M = red_v[0];
  __syncthreads();
  float p[16]; float esum = 0.f;
#pragma unroll
  for (int i = 0; i < 16; i++) { p[i] = __expf(lg[i] - M); esum += p[i]; }
  red_v[t] = esum; __syncthreads();
  for (int o = 128; o > 0; o >>= 1) { if (t < o) red_v[t] += red_v[t + o]; __syncthreads(); }
  const float inv = 1.f / red_v[0];
  __syncthreads();
#pragma unroll
  for (int i = 0; i < 16; i++) p[i] *= inv;

  // stage rin into Vb[1] interior (halo stays 0) to get shifted-neighbor rin
#pragma unroll
  for (int r = 0; r < 4; r++) {
    floatx4 rr = { rin[r * 4 + 0], rin[r * 4 + 1], rin[r * 4 + 2], rin[r * 4 + 3] };
    *(floatx4*)&Vb[1][VOFF(h0 + r, w0)] = rr;
  }
  __syncthreads();
  // c_d = rin[nbr_d] - rout*(rin[nbr_d] != 0); constant across sweeps
  float cu[16], cdn[16], cl[16], cr[16];
#pragma unroll
  for (int r = 0; r < 4; r++) {
#pragma unroll
    for (int c = 0; c < 4; c++) {
      const int i = r * 4 + c, h = h0 + r, w = w0 + c;
      const float nu = Vb[1][VOFF(h - 1, w)];
      const float nd = Vb[1][VOFF(h + 1, w)];
      const float nl = Vb[1][VOFF(h, w - 1)];
      const float nr = Vb[1][VOFF(h, w + 1)];
      cu [i] = nu - (nu != 0.f ? rout[i] : 0.f);
      cdn[i] = nd - (nd != 0.f ? rout[i] : 0.f);
      cl [i] = nl - (nl != 0.f ? rout[i] : 0.f);
      cr [i] = nr - (nr != 0.f ? rout[i] : 0.f);
    }
  }
  __syncthreads();   // all c_d reads of Vb[1] done before sweep 0 overwrites it

  float v[16];
#pragma unroll
  for (int i = 0; i < 16; i++) v[i] = 0.f;

  // K=64 Jacobi sweeps: V_new = max(V, max_d(p*V[nbr_d] + c_d)), ping-pong LDS
  for (int k = 0; k < 64; k++) {
    const float* Vc = Vb[k & 1];
    float* Vn = Vb[(k & 1) ^ 1];
    const floatx4 top = *(const floatx4*)&Vc[VOFF(h0 - 1, w0)];
    const floatx4 bot = *(const floatx4*)&Vc[VOFF(h0 + 4, w0)];
    float lf[4], rt[4];
#pragma unroll
    for (int r = 0; r < 4; r++) { lf[r] = Vc[VOFF(h0 + r, w0 - 1)]; rt[r] = Vc[VOFF(h0 + r, w0 + 4)]; }
    float nv[16];
#pragma unroll
    for (int r = 0; r < 4; r++) {
#pragma unroll
      for (int c = 0; c < 4; c++) {
        const int i = r * 4 + c;
        const float vu = (r == 0) ? top[c] : v[i - 4];
        const float vd = (r == 3) ? bot[c] : v[i + 4];
        const float vl = (c == 0) ? lf[r] : v[i - 1];
        const float vr = (c == 3) ? rt[r] : v[i + 1];
        const float m1 = fmaxf(fmaf(p[i], vu, cu[i]), fmaf(p[i], vd, cdn[i]));
        const float m2 = fmaxf(fmaf(p[i], vl, cl[i]), fmaf(p[i], vr, cr[i]));
        nv[i] = fmaxf(v[i], fmaxf(m1, m2));
      }
    }
#pragma unroll
    for (int r = 0; r < 4; r++) {
      floatx4 w4 = { nv[r * 4 + 0], nv[r * 4 + 1], nv[r * 4 + 2], nv[r * 4 + 3] };
      *(floatx4*)&Vn[VOFF(h0 + r, w0)] = w4;
    }
#pragma unroll
    for (int i = 0; i < 16; i++) v[i] = nv[i];
    __syncthreads();
  }
  // final V is in Vb[0] (k=63 wrote buffer 0)

  // argmax over obs channel 1 (first-occurrence tie-break = min index)
  float amax = -3.4e38f; int aidx = 0;
#pragma unroll
  for (int r = 0; r < 4; r++) {
#pragma unroll
    for (int c = 0; c < 4; c++) {
      const int cell = (h0 + r) * 64 + (w0 + c);
      const float val = obs[(size_t)b * N_DIM + 3 * cell + 1];
      if (val > amax) { amax = val; aidx = cell; }
    }
  }
  red_v[t] = amax; red_i[t] = aidx;
  __syncthreads();
  for (int o = 128; o > 0; o >>= 1) {
    if (t < o) {
      const float v2 = red_v[t + o]; const int i2 = red_i[t + o];
      if (v2 > red_v[t] || (v2 == red_v[t] && i2 < red_i[t])) { red_v[t] = v2; red_i[t] = i2; }
    }
    __syncthreads();
  }
  const int pos = red_i[0];
  const int pi = pos >> 6, pj = pos & 63;
  __syncthreads();

  // 3x3x4 patch (channels 0..2 = obs, 3 = V; zero-padded borders)
  if (t < 36) {
    const int di = t / 12, rem = t % 12, dj = rem / 4, c4 = rem & 3;
    const int hh = pi - 1 + di, ww = pj - 1 + dj;
    float pv;
    if (c4 < 3) {
      pv = (hh >= 0 && hh < 64 && ww >= 0 && ww < 64)
           ? obs[(size_t)b * N_DIM + 3 * (hh * 64 + ww) + c4] : 0.f;
    } else {
      pv = Vb[0][VOFF(hh, ww)];   // halo provides the zero padding
    }
    red_v[t] = pv;
  }
  __syncthreads();
  if (t < 16) {
    float a = b1[t];
#pragma unroll
    for (int j = 0; j < 36; j++) a = fmaf(red_v[j], w1[j * 16 + t], a);
    red_v[64 + t] = fmaxf(a, 0.f);
  }
  __syncthreads();
  if (t < 4) {
    float a = b2[t];
#pragma unroll
    for (int i = 0; i < 16; i++) a = fmaf(red_v[64 + i], w2[i * 4 + t], a);
    out[b * 4 + t] = a;
  }
}

extern "C" void kernel_launch(void* const* d_in, const int* in_sizes, int n_in,
                              void* d_out, int out_size, void* d_ws, size_t ws_size,
                              hipStream_t stream)
{
  (void)in_sizes; (void)n_in; (void)out_size; (void)ws_size;
  const float* obs  = (const float*)d_in[0];
  const float* phiw = (const float*)d_in[1];
  const float* phib = (const float*)d_in[2];
  const float* w1   = (const float*)d_in[3];
  const float* b1   = (const float*)d_in[4];
  const float* w2   = (const float*)d_in[5];
  const float* b2   = (const float*)d_in[6];
  float* phi = (float*)d_ws;            // 4 * 64 * 12288 fp32 = 12.6 MB scratch
  float* out = (float*)d_out;

  hipLaunchKernelGGL(gemm_phi, dim3(N_DIM / NTILE, SPLITK), dim3(256), 0, stream,
                     obs, phiw, phib, phi);
  hipLaunchKernelGGL(vin_mlp, dim3(64), dim3(256), 0, stream,
                     obs, phi, w1, b1, w2, b2, out);
}

// Round 3
// 815.773 us; speedup vs baseline: 1.0047x; 1.0047x over previous
//
#include <hip/hip_runtime.h>
#include <hip/hip_bf16.h>

typedef __attribute__((ext_vector_type(8))) short short8;
typedef __attribute__((ext_vector_type(4))) float floatx4;
typedef __attribute__((ext_vector_type(4))) unsigned short ushort4v;
typedef __attribute__((ext_vector_type(8))) unsigned short ushort8v;

#define N_DIM 12288
#define SPLITK 16
#define KCHUNK (N_DIM / SPLITK)   // 768
#define KSTEP 32
#define KITERS (KCHUNK / KSTEP)   // 24
#define NTILE 256
#define WSTR 40                   // LDS row stride in bf16 elems (32 + 8 pad)

__device__ __forceinline__ unsigned short f2bf(float f) {
  union { float f; unsigned int i; } x; x.f = f;
  unsigned int r = x.i + 0x7fffu + ((x.i >> 16) & 1u);   // RNE
  return (unsigned short)(r >> 16);
}

// ---------------------------------------------------------------------------
// Kernel 1: phi_part[s] = obs[64 x 768_s] @ W[768_s x 12288] (+bias s==0)
// v4: NTILE=256 so each k-row of W is read as 1KB contiguous (DRAM row-buffer
// locality); 512 threads / 8 waves (4m x 2n); KSTEP=32; single-buffer LDS with
// raw s_barrier + lgkmcnt (vmcnt never drained in the loop); 2-deep register
// prefetch (two named sets, 2-unrolled loop). grid=(48,16), block=512.
// ---------------------------------------------------------------------------
__global__ __launch_bounds__(512) void gemm_phi(
    const float* __restrict__ obs, const float* __restrict__ W,
    const float* __restrict__ bias, float* __restrict__ phi_part)
{
  __shared__ unsigned short A_s[64 * WSTR];      // 5120 B   [m][k]
  __shared__ unsigned short W_s[NTILE * WSTR];   // 20480 B  [n][k] (transposed)

  const int t = threadIdx.x;                 // 0..511
  const int n0 = blockIdx.x * NTILE;
  const int s  = blockIdx.y;
  const int k0 = s * KCHUNK;
  const int lane = t & 63, wv = t >> 6;      // 8 waves
  const int l16 = lane & 15, q = lane >> 4;
  const int wm = wv & 3, wn = wv >> 2;       // wave tile: rows 16*wm, cols 128*wn

  // A staging: thread -> row am (0..63), 4 consecutive k
  const int am = t >> 3, ac = (t & 7) * 4;
  const float* aptr = obs + (size_t)am * N_DIM + k0 + ac;

  // W staging: thread -> 1 column (n), 16 consecutive k-rows
  const int wn_idx = 64 * (wv & 3) + lane;   // n offset within tile: 0..255
  const int wkg    = (wv >> 2) * 16;         // k offset within step: 0 or 16
  const float* wptr = W + (size_t)(k0 + wkg) * N_DIM + (n0 + wn_idx);

  // two named prefetch sets (constant-index arrays only -> stay in VGPRs)
  floatx4 pa, qa;
  float pw[16], qw[16];

#define LOADS(AV, WA, TI) do {                                               \
    AV = *(const floatx4*)(aptr + (size_t)(TI) * KSTEP);                     \
    _Pragma("unroll")                                                        \
    for (int j = 0; j < 16; ++j)                                             \
      WA[j] = wptr[(size_t)((TI) * KSTEP + j) * N_DIM];                      \
  } while (0)

#define CONVSTORE(AV, WA) do {                                               \
    ushort4v ua = { f2bf(AV[0]), f2bf(AV[1]), f2bf(AV[2]), f2bf(AV[3]) };    \
    *(ushort4v*)&A_s[am * WSTR + ac] = ua;                                   \
    ushort8v u0, u1;                                                         \
    _Pragma("unroll")                                                        \
    for (int j = 0; j < 8; ++j) { u0[j] = f2bf(WA[j]); u1[j] = f2bf(WA[8 + j]); } \
    *(ushort8v*)&W_s[wn_idx * WSTR + wkg]     = u0;                          \
    *(ushort8v*)&W_s[wn_idx * WSTR + wkg + 8] = u1;                          \
  } while (0)

  // prologue: tiles 0 and 1 in flight (34 outstanding loads)
  LOADS(pa, pw, 0);
  LOADS(qa, qw, 1);

  floatx4 acc[8];
#pragma unroll
  for (int i = 0; i < 8; i++) acc[i] = (floatx4){0.f, 0.f, 0.f, 0.f};

#define STEP(TI, AV, WA) do {                                                \
    CONVSTORE(AV, WA);          /* compiler inserts its own vmcnt wait */    \
    if ((TI) + 2 < KITERS) LOADS(AV, WA, (TI) + 2);                          \
    asm volatile("s_waitcnt lgkmcnt(0)" ::: "memory");                       \
    __builtin_amdgcn_s_barrier();                                            \
    __builtin_amdgcn_sched_barrier(0);                                       \
    {                                                                        \
      short8 af = *(const short8*)&A_s[(16 * wm + l16) * WSTR + 8 * q];      \
      _Pragma("unroll")                                                      \
      for (int nt = 0; nt < 8; ++nt) {                                       \
        short8 wf = *(const short8*)&W_s[(128 * wn + 16 * nt + l16) * WSTR + 8 * q]; \
        acc[nt] = __builtin_amdgcn_mfma_f32_16x16x32_bf16(af, wf, acc[nt], 0, 0, 0); \
      }                                                                      \
    }                                                                        \
    asm volatile("s_waitcnt lgkmcnt(0)" ::: "memory");                       \
    __builtin_amdgcn_s_barrier();   /* all frag reads done before overwrite */ \
    __builtin_amdgcn_sched_barrier(0);                                       \
  } while (0)

  for (int it = 0; it < KITERS; it += 2) {
    STEP(it,     pa, pw);
    STEP(it + 1, qa, qw);
  }

  // epilogue: C/D layout col=lane&15, row=(lane>>4)*4+r  [m89/m91]; plain stores
  float* dst = phi_part + (size_t)s * 64 * N_DIM;
#pragma unroll
  for (int nt = 0; nt < 8; ++nt) {
    const int ncol = n0 + 128 * wn + 16 * nt + l16;
    const float bv = (s == 0) ? bias[ncol] : 0.f;
#pragma unroll
    for (int r = 0; r < 4; ++r) {
      const int m = 16 * wm + q * 4 + r;
      dst[(size_t)m * N_DIM + ncol] = acc[nt][r] + bv;
    }
  }
#undef STEP
#undef CONVSTORE
#undef LOADS
}

// ---------------------------------------------------------------------------
// Kernel 1b: phi_sum = sum over the 16 split-K partials. grid=768, block=256.
// ---------------------------------------------------------------------------
__global__ __launch_bounds__(256) void reduce_phi(
    const float* __restrict__ part, float* __restrict__ sum)
{
  const size_t g = (size_t)blockIdx.x * 256 + threadIdx.x;   // 0..196607
  const float* p = part + 4 * g;
  floatx4 a = *(const floatx4*)(p);
#pragma unroll
  for (int sp = 1; sp < SPLITK; ++sp)
    a += *(const floatx4*)(p + (size_t)sp * 64 * N_DIM);
  *(floatx4*)(sum + 4 * g) = a;
}

// ---------------------------------------------------------------------------
// Kernel 2: per-batch softmax + K=64 VIN sweeps (ping-pong LDS) + argmax +
// patch + MLP. grid = 64 (one block per batch), block = 256 (4x4 cells/thread)
// ---------------------------------------------------------------------------
#define VSTR 76
#define VOFF(h, w) (((h) + 1) * VSTR + (w) + 4)  // halo grid, interior 16B-aligned

__global__ __launch_bounds__(256) void vin_mlp(
    const float* __restrict__ obs, const float* __restrict__ phi,
    const float* __restrict__ w1, const float* __restrict__ b1,
    const float* __restrict__ w2, const float* __restrict__ b2,
    float* __restrict__ out)
{
  __shared__ float Vb[2][66 * VSTR];
  __shared__ float red_v[256];
  __shared__ int   red_i[256];

  const int b = blockIdx.x;
  const int t = threadIdx.x;
  const int ty = t >> 4, tx = t & 15;
  const int h0 = ty * 4, w0 = tx * 4;

  // zero both V buffers (halo must stay 0; interior = V0 = 0)
  for (int i = t; i < 2 * 66 * VSTR; i += 256) (&Vb[0][0])[i] = 0.f;

  // read phi rows -> rin/rout/logits for own 16 cells
  float rin[16], rout[16], lg[16];
#pragma unroll
  for (int r = 0; r < 4; r++) {
    const int j = 3 * ((h0 + r) * 64 + w0);   // 12 contiguous floats, 16B-aligned
    const floatx4* p4 = (const floatx4*)(phi + (size_t)b * N_DIM + j);
    floatx4 x0 = p4[0], x1 = p4[1], x2 = p4[2];
    float f[12];
#pragma unroll
    for (int c = 0; c < 4; c++) { f[c] = x0[c]; f[4 + c] = x1[c]; f[8 + c] = x2[c]; }
#pragma unroll
    for (int c = 0; c < 4; c++) {
      rin [r * 4 + c] = f[3 * c + 0];
      rout[r * 4 + c] = f[3 * c + 1];
      lg  [r * 4 + c] = f[3 * c + 2];
    }
  }

  // block softmax over the 4096 logits
  float lmax = -3.4e38f;
#pragma unroll
  for (int i = 0; i < 16; i++) lmax = fmaxf(lmax, lg[i]);
  __syncthreads();                       // zero-fill done
  red_v[t] = lmax; __syncthreads();
  for (int o = 128; o > 0; o >>= 1) { if (t < o) red_v[t] = fmaxf(red_v[t], red_v[t + o]); __syncthreads(); }
  const float M = red_v[0];
  __syncthreads();
  float p[16]; float esum = 0.f;
#pragma unroll
  for (int i = 0; i < 16; i++) { p[i] = __expf(lg[i] - M); esum += p[i]; }
  red_v[t] = esum; __syncthreads();
  for (int o = 128; o > 0; o >>= 1) { if (t < o) red_v[t] += red_v[t + o]; __syncthreads(); }
  const float inv = 1.f / red_v[0];
  __syncthreads();
#pragma unroll
  for (int i = 0; i < 16; i++) p[i] *= inv;

  // stage rin into Vb[1] interior (halo stays 0) to get shifted-neighbor rin
#pragma unroll
  for (int r = 0; r < 4; r++) {
    floatx4 rr = { rin[r * 4 + 0], rin[r * 4 + 1], rin[r * 4 + 2], rin[r * 4 + 3] };
    *(floatx4*)&Vb[1][VOFF(h0 + r, w0)] = rr;
  }
  __syncthreads();
  // c_d = rin[nbr_d] - rout*(rin[nbr_d] != 0); constant across sweeps
  float cu[16], cdn[16], cl[16], cr[16];
#pragma unroll
  for (int r = 0; r < 4; r++) {
#pragma unroll
    for (int c = 0; c < 4; c++) {
      const int i = r * 4 + c, h = h0 + r, w = w0 + c;
      const float nu = Vb[1][VOFF(h - 1, w)];
      const float nd = Vb[1][VOFF(h + 1, w)];
      const float nl = Vb[1][VOFF(h, w - 1)];
      const float nr = Vb[1][VOFF(h, w + 1)];
      cu [i] = nu - (nu != 0.f ? rout[i] : 0.f);
      cdn[i] = nd - (nd != 0.f ? rout[i] : 0.f);
      cl [i] = nl - (nl != 0.f ? rout[i] : 0.f);
      cr [i] = nr - (nr != 0.f ? rout[i] : 0.f);
    }
  }
  __syncthreads();   // all c_d reads of Vb[1] done before sweep 0 overwrites it

  float v[16];
#pragma unroll
  for (int i = 0; i < 16; i++) v[i] = 0.f;

  // K=64 Jacobi sweeps: V_new = max(V, max_d(p*V[nbr_d] + c_d)), ping-pong LDS
  for (int k = 0; k < 64; k++) {
    const float* Vc = Vb[k & 1];
    float* Vn = Vb[(k & 1) ^ 1];
    const floatx4 top = *(const floatx4*)&Vc[VOFF(h0 - 1, w0)];
    const floatx4 bot = *(const floatx4*)&Vc[VOFF(h0 + 4, w0)];
    float lf[4], rt[4];
#pragma unroll
    for (int r = 0; r < 4; r++) { lf[r] = Vc[VOFF(h0 + r, w0 - 1)]; rt[r] = Vc[VOFF(h0 + r, w0 + 4)]; }
    float nv[16];
#pragma unroll
    for (int r = 0; r < 4; r++) {
#pragma unroll
      for (int c = 0; c < 4; c++) {
        const int i = r * 4 + c;
        const float vu = (r == 0) ? top[c] : v[i - 4];
        const float vd = (r == 3) ? bot[c] : v[i + 4];
        const float vl = (c == 0) ? lf[r] : v[i - 1];
        const float vr = (c == 3) ? rt[r] : v[i + 1];
        const float m1 = fmaxf(fmaf(p[i], vu, cu[i]), fmaf(p[i], vd, cdn[i]));
        const float m2 = fmaxf(fmaf(p[i], vl, cl[i]), fmaf(p[i], vr, cr[i]));
        nv[i] = fmaxf(v[i], fmaxf(m1, m2));
      }
    }
#pragma unroll
    for (int r = 0; r < 4; r++) {
      floatx4 w4 = { nv[r * 4 + 0], nv[r * 4 + 1], nv[r * 4 + 2], nv[r * 4 + 3] };
      *(floatx4*)&Vn[VOFF(h0 + r, w0)] = w4;
    }
#pragma unroll
    for (int i = 0; i < 16; i++) v[i] = nv[i];
    __syncthreads();
  }
  // final V is in Vb[0] (k=63 wrote buffer 0)

  // argmax over obs channel 1 (first-occurrence tie-break = min index)
  float amax = -3.4e38f; int aidx = 0;
#pragma unroll
  for (int r = 0; r < 4; r++) {
#pragma unroll
    for (int c = 0; c < 4; c++) {
      const int cell = (h0 + r) * 64 + (w0 + c);
      const float val = obs[(size_t)b * N_DIM + 3 * cell + 1];
      if (val > amax) { amax = val; aidx = cell; }
    }
  }
  red_v[t] = amax; red_i[t] = aidx;
  __syncthreads();
  for (int o = 128; o > 0; o >>= 1) {
    if (t < o) {
      const float v2 = red_v[t + o]; const int i2 = red_i[t + o];
      if (v2 > red_v[t] || (v2 == red_v[t] && i2 < red_i[t])) { red_v[t] = v2; red_i[t] = i2; }
    }
    __syncthreads();
  }
  const int pos = red_i[0];
  const int pi = pos >> 6, pj = pos & 63;
  __syncthreads();

  // 3x3x4 patch (channels 0..2 = obs, 3 = V; zero-padded borders)
  if (t < 36) {
    const int di = t / 12, rem = t % 12, dj = rem / 4, c4 = rem & 3;
    const int hh = pi - 1 + di, ww = pj - 1 + dj;
    float pv;
    if (c4 < 3) {
      pv = (hh >= 0 && hh < 64 && ww >= 0 && ww < 64)
           ? obs[(size_t)b * N_DIM + 3 * (hh * 64 + ww) + c4] : 0.f;
    } else {
      pv = Vb[0][VOFF(hh, ww)];   // halo provides the zero padding
    }
    red_v[t] = pv;
  }
  __syncthreads();
  if (t < 16) {
    float a = b1[t];
#pragma unroll
    for (int j = 0; j < 36; j++) a = fmaf(red_v[j], w1[j * 16 + t], a);
    red_v[64 + t] = fmaxf(a, 0.f);
  }
  __syncthreads();
  if (t < 4) {
    float a = b2[t];
#pragma unroll
    for (int i = 0; i < 16; i++) a = fmaf(red_v[64 + i], w2[i * 4 + t], a);
    out[b * 4 + t] = a;
  }
}

extern "C" void kernel_launch(void* const* d_in, const int* in_sizes, int n_in,
                              void* d_out, int out_size, void* d_ws, size_t ws_size,
                              hipStream_t stream)
{
  (void)in_sizes; (void)n_in; (void)out_size; (void)ws_size;
  const float* obs  = (const float*)d_in[0];
  const float* phiw = (const float*)d_in[1];
  const float* phib = (const float*)d_in[2];
  const float* w1   = (const float*)d_in[3];
  const float* b1   = (const float*)d_in[4];
  const float* w2   = (const float*)d_in[5];
  const float* b2   = (const float*)d_in[6];
  float* phi_part = (float*)d_ws;                          // 16 * 3.1 MB = 50.3 MB
  float* phi_sum  = phi_part + (size_t)SPLITK * 64 * N_DIM; // 3.1 MB
  float* out = (float*)d_out;

  hipLaunchKernelGGL(gemm_phi, dim3(N_DIM / NTILE, SPLITK), dim3(512), 0, stream,
                     obs, phiw, phib, phi_part);
  hipLaunchKernelGGL(reduce_phi, dim3(64 * N_DIM / 4 / 256), dim3(256), 0, stream,
                     phi_part, phi_sum);
  hipLaunchKernelGGL(vin_mlp, dim3(64), dim3(256), 0, stream,
                     obs, phi_sum, w1, b1, w2, b2, out);
}